// Round 1
// baseline (754.297 us; speedup 1.0000x reference)
//
#include <hip/hip_runtime.h>
#include <hip/hip_bf16.h>

// FluxAttention on MI355X (gfx950). Round 7 = round 6 + 256x256 8-phase qkv:
//  - qkv GEMM rebuilt on the 256²/BK=64/8-wave 8-phase counted-vmcnt template
//    (T2 swizzle + T3/T4 counted vmcnt(6) + T5 setprio). 2 K-tiles per
//    iteration, 4 phases each (K-half x M-half quadrant, 16 MFMA/phase),
//    staging stream derived so every global_load_lds targets an LDS region
//    whose last ds_read was lgkm-waited+barriered earlier (race-free).
//  - XCD-bijective block swizzle (360%8==0), bn-fastest so concurrent blocks
//    on one XCD share a single L2-resident A tile.
//  - outproj keeps the 128² core (only 120 blocks at 256² -> tail-bound).
//  - Flash / casts / norm_rope / merge unchanged from round 6.

typedef __hip_bfloat16 bf16;
typedef __attribute__((ext_vector_type(8))) short short8;
typedef __attribute__((ext_vector_type(4))) short s16x4;
typedef __attribute__((ext_vector_type(4))) float f32x4;

#define KDIM 3072
#define S_TXT 512
#define S_IMG 2048
#define S_ALL 2560
#define NHEADS 24
#define HDIM 128
#define WELEM (KDIM * KDIM)
#define AELEM (S_ALL * KDIM)
#define NSPLIT 3
#define NT_K 48  // K tiles of 64 in the 256x256 GEMM

__device__ __forceinline__ void async_ld16(const void* g, void* l) {
  __builtin_amdgcn_global_load_lds((__attribute__((address_space(1))) void*)g,
                                   (__attribute__((address_space(3))) void*)l,
                                   16, 0, 0);
}

__device__ __forceinline__ short bf16_bits(float x) {
  bf16 h = (bf16)x;
  return __builtin_bit_cast(short, h);
}
__device__ __forceinline__ float bits_f32(short s) {
  return (float)__builtin_bit_cast(bf16, s);
}

__device__ __forceinline__ void phase_mid() {
  __builtin_amdgcn_s_barrier();
  asm volatile("s_waitcnt lgkmcnt(0)" ::: "memory");
  __builtin_amdgcn_sched_barrier(0);
  __builtin_amdgcn_s_setprio(1);
}
__device__ __forceinline__ void phase_end() {
  __builtin_amdgcn_s_setprio(0);
  __builtin_amdgcn_s_barrier();
}

// ---------------------------------------------------------------------------
// Cast kernels: f32 -> bf16, 8 elems/thread, 16B stores.
// ---------------------------------------------------------------------------
__global__ __launch_bounds__(256) void cast_weights_kernel(
    const float* __restrict__ w0, const float* __restrict__ w1,
    const float* __restrict__ w2, const float* __restrict__ w3,
    const float* __restrict__ w4, const float* __restrict__ w5,
    const float* __restrict__ w6, const float* __restrict__ w7,
    bf16* __restrict__ dst) {
  const float* srcs[8] = {w0, w1, w2, w3, w4, w5, w6, w7};
  const float* __restrict__ src = srcs[blockIdx.y];
  bf16* __restrict__ out = dst + (size_t)blockIdx.y * WELEM;
  const size_t i0 = ((size_t)blockIdx.x * 256 + threadIdx.x) * 8;
  const float4 f0 = *(const float4*)(src + i0);
  const float4 f1 = *(const float4*)(src + i0 + 4);
  short8 o;
  o[0] = bf16_bits(f0.x); o[1] = bf16_bits(f0.y);
  o[2] = bf16_bits(f0.z); o[3] = bf16_bits(f0.w);
  o[4] = bf16_bits(f1.x); o[5] = bf16_bits(f1.y);
  o[6] = bf16_bits(f1.z); o[7] = bf16_bits(f1.w);
  *(short8*)(out + i0) = o;
}

// XE rows: [0,512) = enc (txt), [512,2560) = x (img) — concat order of the ref.
__global__ __launch_bounds__(256) void cast_acts_kernel(
    const float* __restrict__ x, const float* __restrict__ enc,
    bf16* __restrict__ xe) {
  const size_t i0 = ((size_t)blockIdx.x * 256 + threadIdx.x) * 8;
  const size_t TXT = (size_t)S_TXT * KDIM;
  const float* __restrict__ src = (i0 < TXT) ? (enc + i0) : (x + (i0 - TXT));
  const float4 f0 = *(const float4*)(src);
  const float4 f1 = *(const float4*)(src + 4);
  short8 o;
  o[0] = bf16_bits(f0.x); o[1] = bf16_bits(f0.y);
  o[2] = bf16_bits(f0.z); o[3] = bf16_bits(f0.w);
  o[4] = bf16_bits(f1.x); o[5] = bf16_bits(f1.y);
  o[6] = bf16_bits(f1.z); o[7] = bf16_bits(f1.w);
  *(short8*)(xe + i0) = o;
}

// ---------------------------------------------------------------------------
// 256x256 NT GEMM, BK=64, 8 waves (512 thr), 8-phase counted-vmcnt schedule.
// C = A * B^T (+bias). A,B bf16 row-major with K contiguous (stride KDIM).
// LDS: [mat][buf(2)][khalf(2)][256 rows][32 cols] shorts = 128 KiB.
// Swizzle: logical 16B slot s of row r stored at phys slot s ^ ((r>>1)&3)
// (2 lanes/bank on ds_read_b128 = free; src-permuted for global_load_lds).
// Phase p of block u (tile u, buf c=u&1): reads quadrant, stages one
// half-tile, barrier, lgkmcnt(0), 16 MFMA under setprio(1), barrier.
// Stage stream: p0 -> (u+1).A.k1 (buf n), p1 -> (u+2).B.k0 (buf c),
// p2 -> (u+2).A.k0, p3 -> (u+2).B.k1. vmcnt(6) at block end guarantees
// tile u+1 fully landed (its newest half is 2 ops older than the newest 6).
// ---------------------------------------------------------------------------
template <typename OutT, bool TRANS>
__device__ __forceinline__ void gemm256(const bf16* __restrict__ Ab,
                                        const bf16* __restrict__ Bb,
                                        OutT* __restrict__ C,
                                        const float* __restrict__ bias,
                                        short* sAmem, short* sBmem) {
  const int tid = threadIdx.x;
  const int lane = tid & 63;
  const int w = tid >> 6;
  const int a = lane & 15;
  const int g = (lane >> 4) & 3;
  const int wm = w >> 2;   // 0..1 -> 128-row slab
  const int wn = w & 3;    // 0..3 -> 64-col slab

  short* const A00 = sAmem;
  short* const A01 = sAmem + 8192;
  short* const A10 = sAmem + 16384;
  short* const A11 = sAmem + 24576;
  short* const B00 = sBmem;
  short* const B01 = sBmem + 8192;
  short* const B10 = sBmem + 16384;
  short* const B11 = sBmem + 24576;

  // Stage one half-tile (256 rows x 32 K-cols) of matrix gb at K offset kbase
  // into LDS block lblk. Dest is lane-linear; source is slot-permuted.
  auto stage = [&](const bf16* gb, int kbase, short* lblk) {
#pragma unroll
    for (int l = 0; l < 2; l++) {
      const int t = l * 512 + tid;
      const int row = t >> 2;
      const int ls = (t & 3) ^ ((row >> 1) & 3);
      async_ld16(gb + (size_t)row * KDIM + kbase + ls * 8,
                 lblk + (l * 512 + w * 64) * 8);
    }
  };
  auto frag = [&](const short* lblk, int R) -> short8 {
    return *(const short8*)(lblk + R * 32 + ((g ^ ((R >> 1) & 3)) * 8));
  };

  f32x4 acc[8][4] = {};

  // Prologue: tile0 fully + tile1 {B.k0, A.k0, B.k1}; A.k1 of tile1 staged
  // at block0 p0. vmcnt(6) leaves tile1's 6 ops in flight, tile0 landed.
  stage(Bb, 0, B00);
  stage(Ab, 0, A00);
  stage(Bb, 32, B01);
  stage(Ab, 32, A01);
  stage(Bb, 64, B10);
  stage(Ab, 64, A10);
  stage(Bb, 96, B11);
  asm volatile("s_waitcnt vmcnt(6)" ::: "memory");
  __builtin_amdgcn_s_barrier();

  const int ra = wm * 128 + a;
  const int rb = wn * 64 + a;

  auto kblock = [&](int u, short* cA0, short* cA1, short* cB0, short* cB1,
                    short* nA1) {
    short8 af[4], bfr[4];
    // ---- phase 0: kh0, mi 0-3 ----
#pragma unroll
    for (int i = 0; i < 4; i++) af[i] = frag(cA0, ra + i * 16);
#pragma unroll
    for (int j = 0; j < 4; j++) bfr[j] = frag(cB0, rb + j * 16);
    if (u + 1 < NT_K) stage(Ab, (u + 1) * 64 + 32, nA1);
    phase_mid();
#pragma unroll
    for (int i = 0; i < 4; i++)
#pragma unroll
      for (int j = 0; j < 4; j++)
        acc[i][j] = __builtin_amdgcn_mfma_f32_16x16x32_bf16(af[i], bfr[j], acc[i][j], 0, 0, 0);
    phase_end();
    // ---- phase 1: kh0, mi 4-7 (B frags persist) ----
#pragma unroll
    for (int i = 0; i < 4; i++) af[i] = frag(cA0, ra + (i + 4) * 16);
    if (u + 2 < NT_K) stage(Bb, (u + 2) * 64, cB0);
    phase_mid();
#pragma unroll
    for (int i = 0; i < 4; i++)
#pragma unroll
      for (int j = 0; j < 4; j++)
        acc[i + 4][j] = __builtin_amdgcn_mfma_f32_16x16x32_bf16(af[i], bfr[j], acc[i + 4][j], 0, 0, 0);
    phase_end();
    // ---- phase 2: kh1, mi 0-3 ----
#pragma unroll
    for (int i = 0; i < 4; i++) af[i] = frag(cA1, ra + i * 16);
#pragma unroll
    for (int j = 0; j < 4; j++) bfr[j] = frag(cB1, rb + j * 16);
    if (u + 2 < NT_K) stage(Ab, (u + 2) * 64, cA0);
    phase_mid();
#pragma unroll
    for (int i = 0; i < 4; i++)
#pragma unroll
      for (int j = 0; j < 4; j++)
        acc[i][j] = __builtin_amdgcn_mfma_f32_16x16x32_bf16(af[i], bfr[j], acc[i][j], 0, 0, 0);
    phase_end();
    // ---- phase 3: kh1, mi 4-7; counted vmcnt at block end ----
#pragma unroll
    for (int i = 0; i < 4; i++) af[i] = frag(cA1, ra + (i + 4) * 16);
    if (u + 2 < NT_K) stage(Bb, (u + 2) * 64 + 32, cB1);
    __builtin_amdgcn_s_barrier();
    asm volatile("s_waitcnt lgkmcnt(0)" ::: "memory");
    __builtin_amdgcn_sched_barrier(0);
    __builtin_amdgcn_s_setprio(1);
#pragma unroll
    for (int i = 0; i < 4; i++)
#pragma unroll
      for (int j = 0; j < 4; j++)
        acc[i + 4][j] = __builtin_amdgcn_mfma_f32_16x16x32_bf16(af[i], bfr[j], acc[i + 4][j], 0, 0, 0);
    __builtin_amdgcn_s_setprio(0);
    if (u < NT_K - 2)
      asm volatile("s_waitcnt vmcnt(6)" ::: "memory");
    else
      asm volatile("s_waitcnt vmcnt(0)" ::: "memory");
    __builtin_amdgcn_s_barrier();
  };

#pragma unroll 1
  for (int u = 0; u < NT_K; u += 2) {
    kblock(u,     A00, A01, B00, B01, A11);
    kblock(u + 1, A10, A11, B10, B11, A01);
  }

  // Epilogue. C/D layout: col = lane&15, row = (lane>>4)*4 + reg.
  if constexpr (TRANS) {
#pragma unroll
    for (int i = 0; i < 8; i++)
#pragma unroll
      for (int j = 0; j < 4; j++) {
        const int col = wn * 64 + j * 16 + a;
        const float bv = bias ? bias[col] : 0.0f;
        s16x4 pk;
#pragma unroll
        for (int r = 0; r < 4; r++) pk[r] = bf16_bits(acc[i][j][r] + bv);
        *(s16x4*)((short*)C + (size_t)col * S_ALL + wm * 128 + i * 16 + g * 4) = pk;
      }
  } else {
#pragma unroll
    for (int i = 0; i < 8; i++)
#pragma unroll
      for (int j = 0; j < 4; j++) {
        const int col = wn * 64 + j * 16 + a;
        const float bv = bias ? bias[col] : 0.0f;
#pragma unroll
        for (int r = 0; r < 4; r++) {
          const int row = wm * 128 + i * 16 + g * 4 + r;
          C[(size_t)row * KDIM + col] = (OutT)(acc[i][j][r] + bv);
        }
      }
  }
}

// Fused QKV projection: 1D grid 360 = 10 row-tiles x 36 col-tiles, XCD-swizzled.
__global__ __launch_bounds__(512, 2) void qkv_kernel(
    const bf16* __restrict__ XE, const bf16* __restrict__ Wc,
    const float* __restrict__ bq, const float* __restrict__ bk, const float* __restrict__ bv,
    bf16* __restrict__ Q, bf16* __restrict__ K, bf16* __restrict__ VT) {
  __shared__ alignas(16) short sAmem[4 * 8192];
  __shared__ alignas(16) short sBmem[4 * 8192];
  // Bijective XCD swizzle (360 % 8 == 0): each XCD owns 45 consecutive works.
  const int bid = blockIdx.x;
  const int wk_ = (bid & 7) * 45 + (bid >> 3);
  const int bm = wk_ / 36;        // 0..9  (256 rows each)
  const int bn = wk_ % 36;        // bn-fastest: XCD chunk shares one A tile
  const int which = bn / 12;      // 0=Q 1=K 2=V
  const int nc = (bn % 12) * 256;
  const bool txt = bm < 2;        // rows 0..511 = enc
  const bf16* W = Wc + (size_t)(txt ? (3 + which) : which) * WELEM + (size_t)nc * KDIM;
  const float* bias = nullptr;
  if (txt) bias = ((which == 0) ? bq : (which == 1) ? bk : bv) + nc;
  const int crow = bm * 256;
  const bf16* A = XE + (size_t)crow * KDIM;
  if (which == 2) {
    gemm256<bf16, true>(A, W, VT + (size_t)nc * S_ALL + crow, bias, sAmem, sBmem);
  } else {
    bf16* Out = (which == 0) ? Q : K;
    gemm256<bf16, false>(A, W, Out + (size_t)crow * KDIM + nc, bias, sAmem, sBmem);
  }
}

// ---------------------------------------------------------------------------
// 128x128 NT GEMM tile core (outproj only; 480-block grid keeps CUs full).
// ---------------------------------------------------------------------------
template <typename OutT, bool TRANS>
__device__ __forceinline__ void gemm_tile(const bf16* __restrict__ A,
                                          const bf16* __restrict__ B,
                                          OutT* __restrict__ C,
                                          const float* __restrict__ bias) {
  __shared__ alignas(16) short sA[128 * 32];
  __shared__ alignas(16) short sB[128 * 32];
  const int tid = threadIdx.x;
  const int lane = tid & 63;
  const int w = tid >> 6;
  const int a = lane & 15;
  const int g = lane >> 4;
  const int wm = (w >> 1) * 64;
  const int wn = (w & 1) * 64;

  f32x4 acc[4][4] = {};

  const int s0 = tid, s1 = tid + 256;
  const int r0 = s0 >> 2, b0 = (s0 & 3) ^ ((r0 >> 1) & 3);
  const int r1 = s1 >> 2, b1 = (s1 & 3) ^ ((r1 >> 1) & 3);
  const bf16* gA0 = A + (size_t)r0 * KDIM + b0 * 8;
  const bf16* gA1 = A + (size_t)r1 * KDIM + b1 * 8;
  const bf16* gB0 = B + (size_t)r0 * KDIM + b0 * 8;
  const bf16* gB1 = B + (size_t)r1 * KDIM + b1 * 8;
  short* lA0 = sA + (w * 64) * 8;
  short* lA1 = sA + (256 + w * 64) * 8;
  short* lB0 = sB + (w * 64) * 8;
  short* lB1 = sB + (256 + w * 64) * 8;

  for (int k0 = 0; k0 < KDIM; k0 += 32) {
    __syncthreads();
    async_ld16(gA0 + k0, lA0);
    async_ld16(gA1 + k0, lA1);
    async_ld16(gB0 + k0, lB0);
    async_ld16(gB1 + k0, lB1);
    __syncthreads();
    short8 af[4], bfg[4];
#pragma unroll
    for (int i = 0; i < 4; i++) {
      const int R = wm + i * 16 + a;
      af[i] = *(const short8*)(sA + R * 32 + ((g ^ ((R >> 1) & 3)) * 8));
    }
#pragma unroll
    for (int j = 0; j < 4; j++) {
      const int R = wn + j * 16 + a;
      bfg[j] = *(const short8*)(sB + R * 32 + ((g ^ ((R >> 1) & 3)) * 8));
    }
#pragma unroll
    for (int i = 0; i < 4; i++)
#pragma unroll
      for (int j = 0; j < 4; j++)
        acc[i][j] = __builtin_amdgcn_mfma_f32_16x16x32_bf16(af[i], bfg[j], acc[i][j], 0, 0, 0);
  }

  if constexpr (TRANS) {
#pragma unroll
    for (int i = 0; i < 4; i++)
#pragma unroll
      for (int j = 0; j < 4; j++) {
        const int col = wn + j * 16 + a;
        const float bv = bias ? bias[col] : 0.0f;
        s16x4 pk;
#pragma unroll
        for (int r = 0; r < 4; r++) pk[r] = bf16_bits(acc[i][j][r] + bv);
        *(s16x4*)((short*)C + (size_t)col * S_ALL + wm + i * 16 + g * 4) = pk;
      }
  } else {
#pragma unroll
    for (int i = 0; i < 4; i++)
#pragma unroll
      for (int j = 0; j < 4; j++) {
        const int col = wn + j * 16 + a;
        const float bv = bias ? bias[col] : 0.0f;
#pragma unroll
        for (int r = 0; r < 4; r++) {
          const int row = wm + i * 16 + g * 4 + r;
          C[(size_t)row * KDIM + col] = (OutT)(acc[i][j][r] + bv);
        }
      }
  }
}

// Output projection: grid (20, 24). d_out: img (2048x3072) then enc (512x3072), f32.
__global__ __launch_bounds__(256) void outproj_kernel(
    const bf16* __restrict__ Obuf, const bf16* __restrict__ Wc,
    const float* __restrict__ b_out, const float* __restrict__ b_add,
    float* __restrict__ out) {
  const int bm = blockIdx.x;
  const int bn = blockIdx.y;
  const bool txt = bm < 4;
  const bf16* A = Obuf + (size_t)bm * 128 * KDIM;
  const bf16* W = Wc + (size_t)(txt ? 7 : 6) * WELEM;
  const float* bias = txt ? b_add : b_out;
  float* C = txt ? (out + (size_t)S_IMG * KDIM + (size_t)bm * 128 * KDIM)
                 : (out + (size_t)(bm - 4) * 128 * KDIM);
  gemm_tile<float, false>(A, W + (size_t)bn * 128 * KDIM, C + bn * 128, bias + bn * 128);
}

// RMS-norm + RoPE in-place. Q additionally pre-scaled by (1/sqrt(128))*log2(e)
// so the QK^T MFMA in flash emits exp2-domain scores directly.
__global__ __launch_bounds__(256) void norm_rope_kernel(
    bf16* __restrict__ Q, bf16* __restrict__ K,
    const float* __restrict__ rc, const float* __restrict__ rs,
    const float* __restrict__ nqw, const float* __restrict__ nkw,
    const float* __restrict__ naqw, const float* __restrict__ nakw) {
  const int row = blockIdx.x;
  const int h = blockIdx.y * 4 + (threadIdx.x >> 6);
  const int t = threadIdx.x & 63;
  const long base = (long)row * KDIM + h * HDIM;
  const int d0 = 2 * t, d1 = d0 + 1;
  const bool txt = row < S_TXT;
  const float QSCL = 0.08838834764831845f * 1.4426950408889634f;
  float qa = (float)Q[base + d0], qb = (float)Q[base + d1];
  float ka = (float)K[base + d0], kb = (float)K[base + d1];
  float sq = qa * qa + qb * qb;
  float sk = ka * ka + kb * kb;
#pragma unroll
  for (int m = 1; m < 64; m <<= 1) {
    sq += __shfl_xor(sq, m);
    sk += __shfl_xor(sk, m);
  }
  const float rq = rsqrtf(sq * (1.0f / 128.0f) + 1e-5f) * QSCL;
  const float rk = rsqrtf(sk * (1.0f / 128.0f) + 1e-5f);
  const float* qw = txt ? naqw : nqw;
  const float* kw = txt ? nakw : nkw;
  const float c0 = rc[row * HDIM + d0], c1 = rc[row * HDIM + d1];
  const float s0 = rs[row * HDIM + d0], s1 = rs[row * HDIM + d1];
  const float qn0 = qa * rq * qw[d0], qn1 = qb * rq * qw[d1];
  const float kn0 = ka * rk * kw[d0], kn1 = kb * rk * kw[d1];
  Q[base + d0] = (bf16)(qn0 * c0 - qn1 * s0);
  Q[base + d1] = (bf16)(qn1 * c1 + qn0 * s1);
  K[base + d0] = (bf16)(kn0 * c0 - kn1 * s0);
  K[base + d1] = (bf16)(kn1 * c1 + kn0 * s1);
}

// ---------------------------------------------------------------------------
// Flash attention, split-KV x3, FIXED-MAX softmax (p = exp2(score), scores
// bounded -> f32-safe). grid (20 q-tiles, 24 heads, 3 splits), 4 waves.
// S^T = K*Q^T so P lands A-operand-friendly; no cross-lane ops in KV loop.
// ---------------------------------------------------------------------------
__global__ __launch_bounds__(256) void flash_kernel(
    const bf16* __restrict__ Q, const bf16* __restrict__ Kb,
    const bf16* __restrict__ VT,
    bf16* __restrict__ Op0, bf16* __restrict__ Op1, bf16* __restrict__ Op2,
    float* __restrict__ L) {
  __shared__ alignas(16) short sK[64 * 128];
  __shared__ alignas(16) short sVT[128 * 64];
  __shared__ alignas(16) short sP[4][32 * 72];
  const int tid = threadIdx.x;
  const int lane = tid & 63;
  const int w = tid >> 6;
  const int a = lane & 15;
  const int g = lane >> 4;
  const int qt = blockIdx.x;
  const int h = blockIdx.y;
  const int split = blockIdx.z;
  const int it0 = split * 13;
  const int it1 = (split == 2) ? 40 : (it0 + 13);
  const int qrow0 = qt * 128 + w * 32;
  short* const sPw = sP[w];

  short8 qf[2][4];
#pragma unroll
  for (int mi = 0; mi < 2; mi++)
#pragma unroll
    for (int kk = 0; kk < 4; kk++)
      qf[mi][kk] = *(const short8*)(Q + (size_t)(qrow0 + mi * 16 + a) * KDIM + h * HDIM + kk * 32 + g * 8);

  f32x4 oacc[2][8] = {};
  float lsum[2] = {0.0f, 0.0f};

  for (int it = it0; it < it1; ++it) {
    const int kv0 = it * 64;
    __syncthreads();
#pragma unroll
    for (int is = 0; is < 4; is++) {
      const int s = is * 256 + w * 64 + lane;
      const int kr = s >> 4, p = s & 15;
      const int lb = (p - (kr & 7)) & 15;
      async_ld16(Kb + (size_t)(kv0 + kr) * KDIM + h * HDIM + lb * 8,
                 sK + (is * 256 + w * 64) * 8);
    }
#pragma unroll
    for (int is = 0; is < 4; is++) {
      const int s = is * 256 + w * 64 + lane;
      const int dr = s >> 3, p = s & 7;
      const int lb = (p - (dr & 7)) & 7;
      async_ld16(VT + (size_t)(h * HDIM + dr) * S_ALL + kv0 + lb * 8,
                 sVT + (is * 256 + w * 64) * 8);
    }
    __syncthreads();

    f32x4 st[4][2] = {};
#pragma unroll
    for (int kk = 0; kk < 4; kk++) {
      short8 kf[4];
#pragma unroll
      for (int ni = 0; ni < 4; ni++) {
        const int kr = ni * 16 + a;
        const int p = ((kk * 4 + g) + (kr & 7)) & 15;
        kf[ni] = *(const short8*)(sK + kr * 128 + p * 8);
      }
#pragma unroll
      for (int ni = 0; ni < 4; ni++)
#pragma unroll
        for (int mi = 0; mi < 2; mi++)
          st[ni][mi] = __builtin_amdgcn_mfma_f32_16x16x32_bf16(kf[ni], qf[mi][kk], st[ni][mi], 0, 0, 0);
    }

#pragma unroll
    for (int mi = 0; mi < 2; mi++)
#pragma unroll
      for (int ni = 0; ni < 4; ni++) {
        s16x4 pk;
#pragma unroll
        for (int r = 0; r < 4; r++) {
          const float p = exp2f(st[ni][mi][r]);
          lsum[mi] += p;
          pk[r] = bf16_bits(p);
        }
        *(s16x4*)(sPw + (mi * 16 + a) * 72 + ni * 16 + g * 4) = pk;
      }

#pragma unroll
    for (int ks = 0; ks < 2; ks++) {
      short8 pf[2];
#pragma unroll
      for (int mi = 0; mi < 2; mi++)
        pf[mi] = *(const short8*)(sPw + (mi * 16 + a) * 72 + ks * 32 + g * 8);
#pragma unroll
      for (int nd = 0; nd < 8; nd++) {
        const int dr = nd * 16 + a;
        const int p = ((ks * 4 + g) + (dr & 7)) & 7;
        const short8 vf = *(const short8*)(sVT + dr * 64 + p * 8);
#pragma unroll
        for (int mi = 0; mi < 2; mi++)
          oacc[mi][nd] = __builtin_amdgcn_mfma_f32_16x16x32_bf16(pf[mi], vf, oacc[mi][nd], 0, 0, 0);
      }
    }
  }

#pragma unroll
  for (int mi = 0; mi < 2; mi++) {
    lsum[mi] += __shfl_xor(lsum[mi], 16);
    lsum[mi] += __shfl_xor(lsum[mi], 32);
  }
  bf16* __restrict__ Op = (split == 0) ? Op0 : (split == 1) ? Op1 : Op2;
#pragma unroll
  for (int mi = 0; mi < 2; mi++) {
#pragma unroll
    for (int r = 0; r < 4; r++) {
      const float inv = 1.0f / __shfl(lsum[mi], g * 4 + r);
      const size_t row = qrow0 + mi * 16 + g * 4 + r;
#pragma unroll
      for (int nd = 0; nd < 8; nd++)
        Op[row * KDIM + h * HDIM + nd * 16 + a] = (bf16)(oacc[mi][nd][r] * inv);
    }
    if (g == 0)
      L[((size_t)split * NHEADS + h) * S_ALL + qrow0 + mi * 16 + a] = lsum[mi];
  }
}

// Merge 3 KV-split partials: O = sum(l_i * O_i) / sum(l_i). In-place into O0.
__global__ __launch_bounds__(256) void merge_kernel(
    bf16* __restrict__ O0, const bf16* __restrict__ O1, const bf16* __restrict__ O2,
    const float* __restrict__ L) {
  const size_t i0 = ((size_t)blockIdx.x * 256 + threadIdx.x) * 8;
  const int row = (int)(i0 / KDIM);
  const int h = (int)((i0 % KDIM) >> 7);
  const float l0 = L[((size_t)0 * NHEADS + h) * S_ALL + row];
  const float l1 = L[((size_t)1 * NHEADS + h) * S_ALL + row];
  const float l2 = L[((size_t)2 * NHEADS + h) * S_ALL + row];
  const float inv = 1.0f / (l0 + l1 + l2);
  const float w0 = l0 * inv, w1 = l1 * inv, w2 = l2 * inv;
  const short8 v0 = *(const short8*)(O0 + i0);
  const short8 v1 = *(const short8*)(O1 + i0);
  const short8 v2 = *(const short8*)(O2 + i0);
  short8 o;
#pragma unroll
  for (int u = 0; u < 8; u++)
    o[u] = bf16_bits(w0 * bits_f32(v0[u]) + w1 * bits_f32(v1[u]) + w2 * bits_f32(v2[u]));
  *(short8*)(O0 + i0) = o;
}

extern "C" void kernel_launch(void* const* d_in, const int* in_sizes, int n_in,
                              void* d_out, int out_size, void* d_ws, size_t ws_size,
                              hipStream_t stream) {
  const float* x    = (const float*)d_in[0];
  const float* enc  = (const float*)d_in[1];
  const float* rc   = (const float*)d_in[2];
  const float* rs   = (const float*)d_in[3];
  const float* wq   = (const float*)d_in[4];
  const float* wk   = (const float*)d_in[5];
  const float* wv   = (const float*)d_in[6];
  const float* waq  = (const float*)d_in[7];
  const float* wak  = (const float*)d_in[8];
  const float* wav  = (const float*)d_in[9];
  const float* bq   = (const float*)d_in[10];
  const float* bk   = (const float*)d_in[11];
  const float* bv   = (const float*)d_in[12];
  const float* nqw  = (const float*)d_in[13];
  const float* nkw  = (const float*)d_in[14];
  const float* naqw = (const float*)d_in[15];
  const float* nakw = (const float*)d_in[16];
  const float* w_out     = (const float*)d_in[17];
  const float* b_out     = (const float*)d_in[18];
  const float* w_add_out = (const float*)d_in[19];
  const float* b_add_out = (const float*)d_in[20];

  // ws layout (bf16): Wc[8*WELEM] | XE(->Opart2) | Q | K | VT | Obuf(=Opart0)
  //                   | Opart1 | L(f32)   — ~235 MiB total.
  bf16* Wc   = (bf16*)d_ws;
  bf16* XE   = Wc + (size_t)8 * WELEM;
  bf16* Q    = XE + AELEM;
  bf16* K    = Q + AELEM;
  bf16* VT   = K + AELEM;
  bf16* Obuf = VT + AELEM;           // Opart split 0
  bf16* Op1  = Obuf + AELEM;         // Opart split 1
  bf16* Op2  = XE;                   // reuse XE (dead after qkv)
  float* L   = (float*)(Op1 + AELEM);

  cast_weights_kernel<<<dim3(WELEM / 2048, 8), 256, 0, stream>>>(
      wq, wk, wv, waq, wak, wav, w_out, w_add_out, Wc);
  cast_acts_kernel<<<dim3(AELEM / 2048), 256, 0, stream>>>(x, enc, XE);

  qkv_kernel<<<dim3(360), dim3(512), 0, stream>>>(XE, Wc, bq, bk, bv, Q, K, VT);
  norm_rope_kernel<<<dim3(S_ALL, 6), 256, 0, stream>>>(Q, K, rc, rs, nqw, nkw, naqw, nakw);
  flash_kernel<<<dim3(20, NHEADS, NSPLIT), 256, 0, stream>>>(Q, K, VT, Obuf, Op1, Op2, L);
  merge_kernel<<<dim3(AELEM / 2048), 256, 0, stream>>>(Obuf, Op1, Op2, L);
  outproj_kernel<<<dim3(20, NHEADS), 256, 0, stream>>>(Obuf, Wc, b_out, b_add_out,
                                                       (float*)d_out);
}

// Round 2
// 738.461 us; speedup vs baseline: 1.0214x; 1.0214x over previous
//
#include <hip/hip_runtime.h>
#include <hip/hip_bf16.h>

// FluxAttention on MI355X (gfx950). Round 8 = round 7 with the qkv tail fixed:
//  - qkv GEMM: 256x192 tiles -> grid 480 = 10x48 (93.75% CU util vs 70% at
//    360 blocks). 8 waves as 4Mx2N (wave tile 64x96, acc[4][6]). LDS 112 KiB.
//  - Stage stream re-derived for the 2-phase B-frag span: per kblock u,
//    p0 stages {A,B}(u+1).k1 (their buffers' last ds_reads retired in kblock
//    u-1), p1 stages A(u+2).k0 (cA0 reads retire at p0-end), p2 stages
//    B(u+2).k0 (cB0 reads retire at p1-end), p3 stages nothing (cB1 reads
//    retire only at p3-end). Every stage targets an LDS region whose last
//    ds_read was lgkm-waited + barrier-retired in an earlier phase.
//  - B half-tile = 768 slots -> waves 0-3 issue 2 global_load_lds, waves 4-7
//    issue 1. Per-wave-class vmcnt accounting: main loop vmcnt(3) (waves>=4:
//    6 ops/kblock, newest 3 = p1+p2 -> p0 stages landed; waves<4: 8 ops,
//    newest 3 -> p0 landed too). Prologue vmcnt(3); last 2 K-tiles vmcnt(0).
//  - outproj keeps the 128-sq core; flash/casts/norm/merge unchanged.

typedef __hip_bfloat16 bf16;
typedef __attribute__((ext_vector_type(8))) short short8;
typedef __attribute__((ext_vector_type(4))) short s16x4;
typedef __attribute__((ext_vector_type(4))) float f32x4;

#define KDIM 3072
#define S_TXT 512
#define S_IMG 2048
#define S_ALL 2560
#define NHEADS 24
#define HDIM 128
#define WELEM (KDIM * KDIM)
#define AELEM (S_ALL * KDIM)
#define NSPLIT 3
#define NT_K 48   // K tiles of 64
#define QBN 192   // qkv GEMM N-tile

__device__ __forceinline__ void async_ld16(const void* g, void* l) {
  __builtin_amdgcn_global_load_lds((__attribute__((address_space(1))) void*)g,
                                   (__attribute__((address_space(3))) void*)l,
                                   16, 0, 0);
}

__device__ __forceinline__ short bf16_bits(float x) {
  bf16 h = (bf16)x;
  return __builtin_bit_cast(short, h);
}
__device__ __forceinline__ float bits_f32(short s) {
  return (float)__builtin_bit_cast(bf16, s);
}

__device__ __forceinline__ void phase_mid() {
  __builtin_amdgcn_s_barrier();
  asm volatile("s_waitcnt lgkmcnt(0)" ::: "memory");
  __builtin_amdgcn_sched_barrier(0);
  __builtin_amdgcn_s_setprio(1);
}
__device__ __forceinline__ void phase_end() {
  __builtin_amdgcn_s_setprio(0);
  __builtin_amdgcn_s_barrier();
}

// ---------------------------------------------------------------------------
// Cast kernels: f32 -> bf16, 8 elems/thread, 16B stores.
// ---------------------------------------------------------------------------
__global__ __launch_bounds__(256) void cast_weights_kernel(
    const float* __restrict__ w0, const float* __restrict__ w1,
    const float* __restrict__ w2, const float* __restrict__ w3,
    const float* __restrict__ w4, const float* __restrict__ w5,
    const float* __restrict__ w6, const float* __restrict__ w7,
    bf16* __restrict__ dst) {
  const float* srcs[8] = {w0, w1, w2, w3, w4, w5, w6, w7};
  const float* __restrict__ src = srcs[blockIdx.y];
  bf16* __restrict__ out = dst + (size_t)blockIdx.y * WELEM;
  const size_t i0 = ((size_t)blockIdx.x * 256 + threadIdx.x) * 8;
  const float4 f0 = *(const float4*)(src + i0);
  const float4 f1 = *(const float4*)(src + i0 + 4);
  short8 o;
  o[0] = bf16_bits(f0.x); o[1] = bf16_bits(f0.y);
  o[2] = bf16_bits(f0.z); o[3] = bf16_bits(f0.w);
  o[4] = bf16_bits(f1.x); o[5] = bf16_bits(f1.y);
  o[6] = bf16_bits(f1.z); o[7] = bf16_bits(f1.w);
  *(short8*)(out + i0) = o;
}

// XE rows: [0,512) = enc (txt), [512,2560) = x (img) — concat order of the ref.
__global__ __launch_bounds__(256) void cast_acts_kernel(
    const float* __restrict__ x, const float* __restrict__ enc,
    bf16* __restrict__ xe) {
  const size_t i0 = ((size_t)blockIdx.x * 256 + threadIdx.x) * 8;
  const size_t TXT = (size_t)S_TXT * KDIM;
  const float* __restrict__ src = (i0 < TXT) ? (enc + i0) : (x + (i0 - TXT));
  const float4 f0 = *(const float4*)(src);
  const float4 f1 = *(const float4*)(src + 4);
  short8 o;
  o[0] = bf16_bits(f0.x); o[1] = bf16_bits(f0.y);
  o[2] = bf16_bits(f0.z); o[3] = bf16_bits(f0.w);
  o[4] = bf16_bits(f1.x); o[5] = bf16_bits(f1.y);
  o[6] = bf16_bits(f1.z); o[7] = bf16_bits(f1.w);
  *(short8*)(xe + i0) = o;
}

// ---------------------------------------------------------------------------
// 256x192 NT GEMM, BK=64, 8 waves (512 thr) as 4Mx2N (wave tile 64x96),
// 8-phase counted-vmcnt schedule. C = A * B^T (+bias), A/B bf16, K stride KDIM.
// LDS: A 2buf x 2khalf x 256x32 (64 KiB) + B 2buf x 2khalf x 192x32 (48 KiB).
// Swizzle: logical 16B slot s of row r at phys slot s ^ ((r>>1)&3); frag reads
// un-swizzle with phys = g ^ ((R>>1)&3) -> 2 lanes/bank (free).
// ---------------------------------------------------------------------------
template <typename OutT, bool TRANS>
__device__ __forceinline__ void gemm256(const bf16* __restrict__ Ab,
                                        const bf16* __restrict__ Bb,
                                        OutT* __restrict__ C,
                                        const float* __restrict__ bias,
                                        short* sAmem, short* sBmem) {
  const int tid = threadIdx.x;
  const int lane = tid & 63;
  const int w = tid >> 6;
  const int a = lane & 15;
  const int g = (lane >> 4) & 3;
  const int wm = w >> 1;   // 0..3 -> 64-row slab
  const int wn = w & 1;    // 0..1 -> 96-col slab

  short* const A00 = sAmem;              // buf0 kh0
  short* const A01 = sAmem + 8192;       // buf0 kh1
  short* const A10 = sAmem + 16384;      // buf1 kh0
  short* const A11 = sAmem + 24576;      // buf1 kh1
  short* const B00 = sBmem;
  short* const B01 = sBmem + 6144;
  short* const B10 = sBmem + 12288;
  short* const B11 = sBmem + 18432;

  // A half-tile: 256 rows x 32 K = 1024 slots, 2 loads/thread.
  auto stageA = [&](int kbase, short* lblk) {
#pragma unroll
    for (int l = 0; l < 2; l++) {
      const int t = l * 512 + tid;
      const int row = t >> 2;
      const int ls = (t & 3) ^ ((row >> 1) & 3);
      async_ld16(Ab + (size_t)row * KDIM + kbase + ls * 8,
                 lblk + (l * 512 + w * 64) * 8);
    }
  };
  // B half-tile: 192 rows x 32 K = 768 slots; waves 0-3 do the second round.
  auto stageB = [&](int kbase, short* lblk) {
    {
      const int t = tid;
      const int row = t >> 2;
      const int ls = (t & 3) ^ ((row >> 1) & 3);
      async_ld16(Bb + (size_t)row * KDIM + kbase + ls * 8,
                 lblk + (w * 64) * 8);
    }
    if (w < 4) {
      const int t = 512 + tid;
      const int row = t >> 2;
      const int ls = (t & 3) ^ ((row >> 1) & 3);
      async_ld16(Bb + (size_t)row * KDIM + kbase + ls * 8,
                 lblk + (512 + w * 64) * 8);
    }
  };
  auto frag = [&](const short* lblk, int R) -> short8 {
    return *(const short8*)(lblk + R * 32 + ((g ^ ((R >> 1) & 3)) * 8));
  };

  f32x4 acc[4][6] = {};

  // Prologue: tile0 all 4 halves + tile1 {A.k0, B.k0}; tile1 k1 halves are
  // staged at kblock0 p0. vmcnt(3): waves>=4 have 9 ops (tile0 = oldest 6),
  // waves<4 have 12 (tile0 = oldest 8) -> tile0 fully landed for both.
  stageB(0, B00);
  stageA(0, A00);
  stageB(32, B01);
  stageA(32, A01);
  stageA(64, A10);
  stageB(64, B10);
  asm volatile("s_waitcnt vmcnt(3)" ::: "memory");
  __builtin_amdgcn_s_barrier();

  const int ra = wm * 64 + a;
  const int rb = wn * 96 + a;

  auto kblock = [&](int u, short* cA0, short* cA1, short* cB0, short* cB1,
                    short* nA1, short* nB1) {
    short8 af[4], bfr[3];
    // ---- phase 0: kh0, j 0-2. Stage (u+1) k1 halves (their buffers' last
    // ds_reads retired in kblock u-1). ----
#pragma unroll
    for (int i = 0; i < 4; i++) af[i] = frag(cA0, ra + i * 16);
#pragma unroll
    for (int j = 0; j < 3; j++) bfr[j] = frag(cB0, rb + j * 16);
    if (u + 1 < NT_K) {
      stageA((u + 1) * 64 + 32, nA1);
      stageB((u + 1) * 64 + 32, nB1);
    }
    phase_mid();
#pragma unroll
    for (int i = 0; i < 4; i++)
#pragma unroll
      for (int j = 0; j < 3; j++)
        acc[i][j] = __builtin_amdgcn_mfma_f32_16x16x32_bf16(af[i], bfr[j], acc[i][j], 0, 0, 0);
    phase_end();
    // ---- phase 1: kh0, j 3-5 (af persists). Stage A(u+2).k0 (cA0 reads
    // retired at p0 end). ----
#pragma unroll
    for (int j = 0; j < 3; j++) bfr[j] = frag(cB0, rb + (j + 3) * 16);
    if (u + 2 < NT_K) stageA((u + 2) * 64, cA0);
    phase_mid();
#pragma unroll
    for (int i = 0; i < 4; i++)
#pragma unroll
      for (int j = 0; j < 3; j++)
        acc[i][j + 3] = __builtin_amdgcn_mfma_f32_16x16x32_bf16(af[i], bfr[j], acc[i][j + 3], 0, 0, 0);
    phase_end();
    // ---- phase 2: kh1, j 0-2. Stage B(u+2).k0 (cB0 reads retired at p1 end). ----
#pragma unroll
    for (int i = 0; i < 4; i++) af[i] = frag(cA1, ra + i * 16);
#pragma unroll
    for (int j = 0; j < 3; j++) bfr[j] = frag(cB1, rb + j * 16);
    if (u + 2 < NT_K) stageB((u + 2) * 64, cB0);
    phase_mid();
#pragma unroll
    for (int i = 0; i < 4; i++)
#pragma unroll
      for (int j = 0; j < 3; j++)
        acc[i][j] = __builtin_amdgcn_mfma_f32_16x16x32_bf16(af[i], bfr[j], acc[i][j], 0, 0, 0);
    phase_end();
    // ---- phase 3: kh1, j 3-5. No stage (cB1 reads retire only now).
    // vmcnt(3) at block end -> p0's (u+1) k1 stages landed for both wave
    // classes; last 2 kblocks drain with vmcnt(0). ----
#pragma unroll
    for (int j = 0; j < 3; j++) bfr[j] = frag(cB1, rb + (j + 3) * 16);
    __builtin_amdgcn_s_barrier();
    asm volatile("s_waitcnt lgkmcnt(0)" ::: "memory");
    __builtin_amdgcn_sched_barrier(0);
    __builtin_amdgcn_s_setprio(1);
#pragma unroll
    for (int i = 0; i < 4; i++)
#pragma unroll
      for (int j = 0; j < 3; j++)
        acc[i][j + 3] = __builtin_amdgcn_mfma_f32_16x16x32_bf16(af[i], bfr[j], acc[i][j + 3], 0, 0, 0);
    __builtin_amdgcn_s_setprio(0);
    if (u < NT_K - 2)
      asm volatile("s_waitcnt vmcnt(3)" ::: "memory");
    else
      asm volatile("s_waitcnt vmcnt(0)" ::: "memory");
    __builtin_amdgcn_s_barrier();
  };

#pragma unroll 1
  for (int u = 0; u < NT_K; u += 2) {
    kblock(u,     A00, A01, B00, B01, A11, B11);
    kblock(u + 1, A10, A11, B10, B11, A01, B01);
  }

  // Epilogue. C/D layout: col = lane&15, row = (lane>>4)*4 + reg.
  if constexpr (TRANS) {
#pragma unroll
    for (int i = 0; i < 4; i++)
#pragma unroll
      for (int j = 0; j < 6; j++) {
        const int col = wn * 96 + j * 16 + a;
        const float bv = bias ? bias[col] : 0.0f;
        s16x4 pk;
#pragma unroll
        for (int r = 0; r < 4; r++) pk[r] = bf16_bits(acc[i][j][r] + bv);
        *(s16x4*)((short*)C + (size_t)col * S_ALL + wm * 64 + i * 16 + g * 4) = pk;
      }
  } else {
#pragma unroll
    for (int i = 0; i < 4; i++)
#pragma unroll
      for (int j = 0; j < 6; j++) {
        const int col = wn * 96 + j * 16 + a;
        const float bv = bias ? bias[col] : 0.0f;
#pragma unroll
        for (int r = 0; r < 4; r++) {
          const int row = wm * 64 + i * 16 + g * 4 + r;
          C[(size_t)row * KDIM + col] = (OutT)(acc[i][j][r] + bv);
        }
      }
  }
}

// Fused QKV projection: 1D grid 480 = 10 row-tiles x 48 col-tiles (192 wide),
// XCD-bijective swizzle (480 % 8 == 0), bn-fastest for shared A in L2.
__global__ __launch_bounds__(512, 2) void qkv_kernel(
    const bf16* __restrict__ XE, const bf16* __restrict__ Wc,
    const float* __restrict__ bq, const float* __restrict__ bk, const float* __restrict__ bv,
    bf16* __restrict__ Q, bf16* __restrict__ K, bf16* __restrict__ VT) {
  __shared__ alignas(16) short sAmem[4 * 8192];
  __shared__ alignas(16) short sBmem[4 * 6144];
  const int bid = blockIdx.x;
  const int wk_ = (bid & 7) * 60 + (bid >> 3);
  const int bm = wk_ / 48;        // 0..9  (256 rows each)
  const int bn = wk_ % 48;        // bn-fastest within an XCD chunk
  const int which = bn / 16;      // 0=Q 1=K 2=V
  const int nc = (bn % 16) * QBN;
  const bool txt = bm < 2;        // rows 0..511 = enc
  const bf16* W = Wc + (size_t)(txt ? (3 + which) : which) * WELEM + (size_t)nc * KDIM;
  const float* bias = nullptr;
  if (txt) bias = ((which == 0) ? bq : (which == 1) ? bk : bv) + nc;
  const int crow = bm * 256;
  const bf16* A = XE + (size_t)crow * KDIM;
  if (which == 2) {
    gemm256<bf16, true>(A, W, VT + (size_t)nc * S_ALL + crow, bias, sAmem, sBmem);
  } else {
    bf16* Out = (which == 0) ? Q : K;
    gemm256<bf16, false>(A, W, Out + (size_t)crow * KDIM + nc, bias, sAmem, sBmem);
  }
}

// ---------------------------------------------------------------------------
// 128x128 NT GEMM tile core (outproj only; 480 blocks, 2/CU, co-resident).
// ---------------------------------------------------------------------------
template <typename OutT, bool TRANS>
__device__ __forceinline__ void gemm_tile(const bf16* __restrict__ A,
                                          const bf16* __restrict__ B,
                                          OutT* __restrict__ C,
                                          const float* __restrict__ bias) {
  __shared__ alignas(16) short sA[128 * 32];
  __shared__ alignas(16) short sB[128 * 32];
  const int tid = threadIdx.x;
  const int lane = tid & 63;
  const int w = tid >> 6;
  const int a = lane & 15;
  const int g = lane >> 4;
  const int wm = (w >> 1) * 64;
  const int wn = (w & 1) * 64;

  f32x4 acc[4][4] = {};

  const int s0 = tid, s1 = tid + 256;
  const int r0 = s0 >> 2, b0 = (s0 & 3) ^ ((r0 >> 1) & 3);
  const int r1 = s1 >> 2, b1 = (s1 & 3) ^ ((r1 >> 1) & 3);
  const bf16* gA0 = A + (size_t)r0 * KDIM + b0 * 8;
  const bf16* gA1 = A + (size_t)r1 * KDIM + b1 * 8;
  const bf16* gB0 = B + (size_t)r0 * KDIM + b0 * 8;
  const bf16* gB1 = B + (size_t)r1 * KDIM + b1 * 8;
  short* lA0 = sA + (w * 64) * 8;
  short* lA1 = sA + (256 + w * 64) * 8;
  short* lB0 = sB + (w * 64) * 8;
  short* lB1 = sB + (256 + w * 64) * 8;

  for (int k0 = 0; k0 < KDIM; k0 += 32) {
    __syncthreads();
    async_ld16(gA0 + k0, lA0);
    async_ld16(gA1 + k0, lA1);
    async_ld16(gB0 + k0, lB0);
    async_ld16(gB1 + k0, lB1);
    __syncthreads();
    short8 af[4], bfg[4];
#pragma unroll
    for (int i = 0; i < 4; i++) {
      const int R = wm + i * 16 + a;
      af[i] = *(const short8*)(sA + R * 32 + ((g ^ ((R >> 1) & 3)) * 8));
    }
#pragma unroll
    for (int j = 0; j < 4; j++) {
      const int R = wn + j * 16 + a;
      bfg[j] = *(const short8*)(sB + R * 32 + ((g ^ ((R >> 1) & 3)) * 8));
    }
#pragma unroll
    for (int i = 0; i < 4; i++)
#pragma unroll
      for (int j = 0; j < 4; j++)
        acc[i][j] = __builtin_amdgcn_mfma_f32_16x16x32_bf16(af[i], bfg[j], acc[i][j], 0, 0, 0);
  }

  if constexpr (TRANS) {
#pragma unroll
    for (int i = 0; i < 4; i++)
#pragma unroll
      for (int j = 0; j < 4; j++) {
        const int col = wn + j * 16 + a;
        const float bv = bias ? bias[col] : 0.0f;
        s16x4 pk;
#pragma unroll
        for (int r = 0; r < 4; r++) pk[r] = bf16_bits(acc[i][j][r] + bv);
        *(s16x4*)((short*)C + (size_t)col * S_ALL + wm + i * 16 + g * 4) = pk;
      }
  } else {
#pragma unroll
    for (int i = 0; i < 4; i++)
#pragma unroll
      for (int j = 0; j < 4; j++) {
        const int col = wn + j * 16 + a;
        const float bv = bias ? bias[col] : 0.0f;
#pragma unroll
        for (int r = 0; r < 4; r++) {
          const int row = wm + i * 16 + g * 4 + r;
          C[(size_t)row * KDIM + col] = (OutT)(acc[i][j][r] + bv);
        }
      }
  }
}

// Output projection: grid (20, 24). d_out: img (2048x3072) then enc (512x3072), f32.
__global__ __launch_bounds__(256) void outproj_kernel(
    const bf16* __restrict__ Obuf, const bf16* __restrict__ Wc,
    const float* __restrict__ b_out, const float* __restrict__ b_add,
    float* __restrict__ out) {
  const int bm = blockIdx.x;
  const int bn = blockIdx.y;
  const bool txt = bm < 4;
  const bf16* A = Obuf + (size_t)bm * 128 * KDIM;
  const bf16* W = Wc + (size_t)(txt ? 7 : 6) * WELEM;
  const float* bias = txt ? b_add : b_out;
  float* C = txt ? (out + (size_t)S_IMG * KDIM + (size_t)bm * 128 * KDIM)
                 : (out + (size_t)(bm - 4) * 128 * KDIM);
  gemm_tile<float, false>(A, W + (size_t)bn * 128 * KDIM, C + bn * 128, bias + bn * 128);
}

// RMS-norm + RoPE in-place. Q additionally pre-scaled by (1/sqrt(128))*log2(e)
// so the QK^T MFMA in flash emits exp2-domain scores directly.
__global__ __launch_bounds__(256) void norm_rope_kernel(
    bf16* __restrict__ Q, bf16* __restrict__ K,
    const float* __restrict__ rc, const float* __restrict__ rs,
    const float* __restrict__ nqw, const float* __restrict__ nkw,
    const float* __restrict__ naqw, const float* __restrict__ nakw) {
  const int row = blockIdx.x;
  const int h = blockIdx.y * 4 + (threadIdx.x >> 6);
  const int t = threadIdx.x & 63;
  const long base = (long)row * KDIM + h * HDIM;
  const int d0 = 2 * t, d1 = d0 + 1;
  const bool txt = row < S_TXT;
  const float QSCL = 0.08838834764831845f * 1.4426950408889634f;
  float qa = (float)Q[base + d0], qb = (float)Q[base + d1];
  float ka = (float)K[base + d0], kb = (float)K[base + d1];
  float sq = qa * qa + qb * qb;
  float sk = ka * ka + kb * kb;
#pragma unroll
  for (int m = 1; m < 64; m <<= 1) {
    sq += __shfl_xor(sq, m);
    sk += __shfl_xor(sk, m);
  }
  const float rq = rsqrtf(sq * (1.0f / 128.0f) + 1e-5f) * QSCL;
  const float rk = rsqrtf(sk * (1.0f / 128.0f) + 1e-5f);
  const float* qw = txt ? naqw : nqw;
  const float* kw = txt ? nakw : nkw;
  const float c0 = rc[row * HDIM + d0], c1 = rc[row * HDIM + d1];
  const float s0 = rs[row * HDIM + d0], s1 = rs[row * HDIM + d1];
  const float qn0 = qa * rq * qw[d0], qn1 = qb * rq * qw[d1];
  const float kn0 = ka * rk * kw[d0], kn1 = kb * rk * kw[d1];
  Q[base + d0] = (bf16)(qn0 * c0 - qn1 * s0);
  Q[base + d1] = (bf16)(qn1 * c1 + qn0 * s1);
  K[base + d0] = (bf16)(kn0 * c0 - kn1 * s0);
  K[base + d1] = (bf16)(kn1 * c1 + kn0 * s1);
}

// ---------------------------------------------------------------------------
// Flash attention, split-KV x3, FIXED-MAX softmax (p = exp2(score), scores
// bounded -> f32-safe). grid (20 q-tiles, 24 heads, 3 splits), 4 waves.
// S^T = K*Q^T so P lands A-operand-friendly; no cross-lane ops in KV loop.
// ---------------------------------------------------------------------------
__global__ __launch_bounds__(256) void flash_kernel(
    const bf16* __restrict__ Q, const bf16* __restrict__ Kb,
    const bf16* __restrict__ VT,
    bf16* __restrict__ Op0, bf16* __restrict__ Op1, bf16* __restrict__ Op2,
    float* __restrict__ L) {
  __shared__ alignas(16) short sK[64 * 128];
  __shared__ alignas(16) short sVT[128 * 64];
  __shared__ alignas(16) short sP[4][32 * 72];
  const int tid = threadIdx.x;
  const int lane = tid & 63;
  const int w = tid >> 6;
  const int a = lane & 15;
  const int g = lane >> 4;
  const int qt = blockIdx.x;
  const int h = blockIdx.y;
  const int split = blockIdx.z;
  const int it0 = split * 13;
  const int it1 = (split == 2) ? 40 : (it0 + 13);
  const int qrow0 = qt * 128 + w * 32;
  short* const sPw = sP[w];

  short8 qf[2][4];
#pragma unroll
  for (int mi = 0; mi < 2; mi++)
#pragma unroll
    for (int kk = 0; kk < 4; kk++)
      qf[mi][kk] = *(const short8*)(Q + (size_t)(qrow0 + mi * 16 + a) * KDIM + h * HDIM + kk * 32 + g * 8);

  f32x4 oacc[2][8] = {};
  float lsum[2] = {0.0f, 0.0f};

  for (int it = it0; it < it1; ++it) {
    const int kv0 = it * 64;
    __syncthreads();
#pragma unroll
    for (int is = 0; is < 4; is++) {
      const int s = is * 256 + w * 64 + lane;
      const int kr = s >> 4, p = s & 15;
      const int lb = (p - (kr & 7)) & 15;
      async_ld16(Kb + (size_t)(kv0 + kr) * KDIM + h * HDIM + lb * 8,
                 sK + (is * 256 + w * 64) * 8);
    }
#pragma unroll
    for (int is = 0; is < 4; is++) {
      const int s = is * 256 + w * 64 + lane;
      const int dr = s >> 3, p = s & 7;
      const int lb = (p - (dr & 7)) & 7;
      async_ld16(VT + (size_t)(h * HDIM + dr) * S_ALL + kv0 + lb * 8,
                 sVT + (is * 256 + w * 64) * 8);
    }
    __syncthreads();

    f32x4 st[4][2] = {};
#pragma unroll
    for (int kk = 0; kk < 4; kk++) {
      short8 kf[4];
#pragma unroll
      for (int ni = 0; ni < 4; ni++) {
        const int kr = ni * 16 + a;
        const int p = ((kk * 4 + g) + (kr & 7)) & 15;
        kf[ni] = *(const short8*)(sK + kr * 128 + p * 8);
      }
#pragma unroll
      for (int ni = 0; ni < 4; ni++)
#pragma unroll
        for (int mi = 0; mi < 2; mi++)
          st[ni][mi] = __builtin_amdgcn_mfma_f32_16x16x32_bf16(kf[ni], qf[mi][kk], st[ni][mi], 0, 0, 0);
    }

#pragma unroll
    for (int mi = 0; mi < 2; mi++)
#pragma unroll
      for (int ni = 0; ni < 4; ni++) {
        s16x4 pk;
#pragma unroll
        for (int r = 0; r < 4; r++) {
          const float p = exp2f(st[ni][mi][r]);
          lsum[mi] += p;
          pk[r] = bf16_bits(p);
        }
        *(s16x4*)(sPw + (mi * 16 + a) * 72 + ni * 16 + g * 4) = pk;
      }

#pragma unroll
    for (int ks = 0; ks < 2; ks++) {
      short8 pf[2];
#pragma unroll
      for (int mi = 0; mi < 2; mi++)
        pf[mi] = *(const short8*)(sPw + (mi * 16 + a) * 72 + ks * 32 + g * 8);
#pragma unroll
      for (int nd = 0; nd < 8; nd++) {
        const int dr = nd * 16 + a;
        const int p = ((ks * 4 + g) + (dr & 7)) & 7;
        const short8 vf = *(const short8*)(sVT + dr * 64 + p * 8);
#pragma unroll
        for (int mi = 0; mi < 2; mi++)
          oacc[mi][nd] = __builtin_amdgcn_mfma_f32_16x16x32_bf16(pf[mi], vf, oacc[mi][nd], 0, 0, 0);
      }
    }
  }

#pragma unroll
  for (int mi = 0; mi < 2; mi++) {
    lsum[mi] += __shfl_xor(lsum[mi], 16);
    lsum[mi] += __shfl_xor(lsum[mi], 32);
  }
  bf16* __restrict__ Op = (split == 0) ? Op0 : (split == 1) ? Op1 : Op2;
#pragma unroll
  for (int mi = 0; mi < 2; mi++) {
#pragma unroll
    for (int r = 0; r < 4; r++) {
      const float inv = 1.0f / __shfl(lsum[mi], g * 4 + r);
      const size_t row = qrow0 + mi * 16 + g * 4 + r;
#pragma unroll
      for (int nd = 0; nd < 8; nd++)
        Op[row * KDIM + h * HDIM + nd * 16 + a] = (bf16)(oacc[mi][nd][r] * inv);
    }
    if (g == 0)
      L[((size_t)split * NHEADS + h) * S_ALL + qrow0 + mi * 16 + a] = lsum[mi];
  }
}

// Merge 3 KV-split partials: O = sum(l_i * O_i) / sum(l_i). In-place into O0.
__global__ __launch_bounds__(256) void merge_kernel(
    bf16* __restrict__ O0, const bf16* __restrict__ O1, const bf16* __restrict__ O2,
    const float* __restrict__ L) {
  const size_t i0 = ((size_t)blockIdx.x * 256 + threadIdx.x) * 8;
  const int row = (int)(i0 / KDIM);
  const int h = (int)((i0 % KDIM) >> 7);
  const float l0 = L[((size_t)0 * NHEADS + h) * S_ALL + row];
  const float l1 = L[((size_t)1 * NHEADS + h) * S_ALL + row];
  const float l2 = L[((size_t)2 * NHEADS + h) * S_ALL + row];
  const float inv = 1.0f / (l0 + l1 + l2);
  const float w0 = l0 * inv, w1 = l1 * inv, w2 = l2 * inv;
  const short8 v0 = *(const short8*)(O0 + i0);
  const short8 v1 = *(const short8*)(O1 + i0);
  const short8 v2 = *(const short8*)(O2 + i0);
  short8 o;
#pragma unroll
  for (int u = 0; u < 8; u++)
    o[u] = bf16_bits(w0 * bits_f32(v0[u]) + w1 * bits_f32(v1[u]) + w2 * bits_f32(v2[u]));
  *(short8*)(O0 + i0) = o;
}

extern "C" void kernel_launch(void* const* d_in, const int* in_sizes, int n_in,
                              void* d_out, int out_size, void* d_ws, size_t ws_size,
                              hipStream_t stream) {
  const float* x    = (const float*)d_in[0];
  const float* enc  = (const float*)d_in[1];
  const float* rc   = (const float*)d_in[2];
  const float* rs   = (const float*)d_in[3];
  const float* wq   = (const float*)d_in[4];
  const float* wk   = (const float*)d_in[5];
  const float* wv   = (const float*)d_in[6];
  const float* waq  = (const float*)d_in[7];
  const float* wak  = (const float*)d_in[8];
  const float* wav  = (const float*)d_in[9];
  const float* bq   = (const float*)d_in[10];
  const float* bk   = (const float*)d_in[11];
  const float* bv   = (const float*)d_in[12];
  const float* nqw  = (const float*)d_in[13];
  const float* nkw  = (const float*)d_in[14];
  const float* naqw = (const float*)d_in[15];
  const float* nakw = (const float*)d_in[16];
  const float* w_out     = (const float*)d_in[17];
  const float* b_out     = (const float*)d_in[18];
  const float* w_add_out = (const float*)d_in[19];
  const float* b_add_out = (const float*)d_in[20];

  // ws layout (bf16): Wc[8*WELEM] | XE(->Opart2) | Q | K | VT | Obuf(=Opart0)
  //                   | Opart1 | L(f32)   — ~235 MiB total.
  bf16* Wc   = (bf16*)d_ws;
  bf16* XE   = Wc + (size_t)8 * WELEM;
  bf16* Q    = XE + AELEM;
  bf16* K    = Q + AELEM;
  bf16* VT   = K + AELEM;
  bf16* Obuf = VT + AELEM;           // Opart split 0
  bf16* Op1  = Obuf + AELEM;         // Opart split 1
  bf16* Op2  = XE;                   // reuse XE (dead after qkv)
  float* L   = (float*)(Op1 + AELEM);

  cast_weights_kernel<<<dim3(WELEM / 2048, 8), 256, 0, stream>>>(
      wq, wk, wv, waq, wak, wav, w_out, w_add_out, Wc);
  cast_acts_kernel<<<dim3(AELEM / 2048), 256, 0, stream>>>(x, enc, XE);

  qkv_kernel<<<dim3(480), dim3(512), 0, stream>>>(XE, Wc, bq, bk, bv, Q, K, VT);
  norm_rope_kernel<<<dim3(S_ALL, 6), 256, 0, stream>>>(Q, K, rc, rs, nqw, nkw, naqw, nakw);
  flash_kernel<<<dim3(20, NHEADS, NSPLIT), 256, 0, stream>>>(Q, K, VT, Obuf, Op1, Op2, L);
  merge_kernel<<<dim3(AELEM / 2048), 256, 0, stream>>>(Obuf, Op1, Op2, L);
  outproj_kernel<<<dim3(20, NHEADS), 256, 0, stream>>>(Obuf, Wc, b_out, b_add_out,
                                                       (float*)d_out);
}

// Round 3
// 736.756 us; speedup vs baseline: 1.0238x; 1.0023x over previous
//
#include <hip/hip_runtime.h>
#include <hip/hip_bf16.h>

// FluxAttention on MI355X (gfx950). Round 9 = round 8 with the qkv inner loop
// restructured from 8-barrier lockstep phases to 1 barrier per K-tile:
//  - All 20 fragment ds_reads issued up front (pinned into 4 groups with
//    sched_barrier(0) so counted lgkmcnt stays valid), stages for tile u+1
//    issued next (2-buffer depth-1: ~1500 cyc to land), then 4 MFMA groups
//    gated by lgkmcnt(13/10/3/0)+sched_barrier(0)+setprio. LDS drain now
//    overlaps MFMA issue instead of serializing with it; barriers per K-tile
//    drop 8 -> 1 (+1 vmcnt(0) which waits on ~1500-cycle-old loads).
//  - Race safety: stage targets buf[u^1], whose last ds_reads were lgkm-
//    retired before the end-of-(u-1) barrier; per-wave vmcnt(0) precedes the
//    tile-end barrier, so all waves' stage portions land before any wave
//    crosses into tile u+1.
//  - Tile 256x192, 4Mx2N waves, XOR swizzle, grid 480, XCD swizzle: unchanged.
//  - outproj/flash/casts/norm/merge unchanged.

typedef __hip_bfloat16 bf16;
typedef __attribute__((ext_vector_type(8))) short short8;
typedef __attribute__((ext_vector_type(4))) short s16x4;
typedef __attribute__((ext_vector_type(4))) float f32x4;

#define KDIM 3072
#define S_TXT 512
#define S_IMG 2048
#define S_ALL 2560
#define NHEADS 24
#define HDIM 128
#define WELEM (KDIM * KDIM)
#define AELEM (S_ALL * KDIM)
#define NSPLIT 3
#define NT_K 48   // K tiles of 64
#define QBN 192   // qkv GEMM N-tile

__device__ __forceinline__ void async_ld16(const void* g, void* l) {
  __builtin_amdgcn_global_load_lds((__attribute__((address_space(1))) void*)g,
                                   (__attribute__((address_space(3))) void*)l,
                                   16, 0, 0);
}

__device__ __forceinline__ short bf16_bits(float x) {
  bf16 h = (bf16)x;
  return __builtin_bit_cast(short, h);
}
__device__ __forceinline__ float bits_f32(short s) {
  return (float)__builtin_bit_cast(bf16, s);
}

// ---------------------------------------------------------------------------
// Cast kernels: f32 -> bf16, 8 elems/thread, 16B stores.
// ---------------------------------------------------------------------------
__global__ __launch_bounds__(256) void cast_weights_kernel(
    const float* __restrict__ w0, const float* __restrict__ w1,
    const float* __restrict__ w2, const float* __restrict__ w3,
    const float* __restrict__ w4, const float* __restrict__ w5,
    const float* __restrict__ w6, const float* __restrict__ w7,
    bf16* __restrict__ dst) {
  const float* srcs[8] = {w0, w1, w2, w3, w4, w5, w6, w7};
  const float* __restrict__ src = srcs[blockIdx.y];
  bf16* __restrict__ out = dst + (size_t)blockIdx.y * WELEM;
  const size_t i0 = ((size_t)blockIdx.x * 256 + threadIdx.x) * 8;
  const float4 f0 = *(const float4*)(src + i0);
  const float4 f1 = *(const float4*)(src + i0 + 4);
  short8 o;
  o[0] = bf16_bits(f0.x); o[1] = bf16_bits(f0.y);
  o[2] = bf16_bits(f0.z); o[3] = bf16_bits(f0.w);
  o[4] = bf16_bits(f1.x); o[5] = bf16_bits(f1.y);
  o[6] = bf16_bits(f1.z); o[7] = bf16_bits(f1.w);
  *(short8*)(out + i0) = o;
}

// XE rows: [0,512) = enc (txt), [512,2560) = x (img) — concat order of the ref.
__global__ __launch_bounds__(256) void cast_acts_kernel(
    const float* __restrict__ x, const float* __restrict__ enc,
    bf16* __restrict__ xe) {
  const size_t i0 = ((size_t)blockIdx.x * 256 + threadIdx.x) * 8;
  const size_t TXT = (size_t)S_TXT * KDIM;
  const float* __restrict__ src = (i0 < TXT) ? (enc + i0) : (x + (i0 - TXT));
  const float4 f0 = *(const float4*)(src);
  const float4 f1 = *(const float4*)(src + 4);
  short8 o;
  o[0] = bf16_bits(f0.x); o[1] = bf16_bits(f0.y);
  o[2] = bf16_bits(f0.z); o[3] = bf16_bits(f0.w);
  o[4] = bf16_bits(f1.x); o[5] = bf16_bits(f1.y);
  o[6] = bf16_bits(f1.z); o[7] = bf16_bits(f1.w);
  *(short8*)(xe + i0) = o;
}

// ---------------------------------------------------------------------------
// 256x192 NT GEMM, BK=64, 8 waves (512 thr) as 4Mx2N (wave tile 64x96).
// 1-barrier-per-K-tile schedule with counted lgkmcnt overlap (see header).
// LDS: A 2buf x 2khalf x 256x32 (64 KiB) + B 2buf x 2khalf x 192x32 (48 KiB).
// Swizzle: logical 16B slot s of row r at phys slot s ^ ((r>>1)&3); frag reads
// un-swizzle with phys = g ^ ((R>>1)&3) -> 2 lanes/bank (free).
// ---------------------------------------------------------------------------
template <typename OutT, bool TRANS>
__device__ __forceinline__ void gemm256(const bf16* __restrict__ Ab,
                                        const bf16* __restrict__ Bb,
                                        OutT* __restrict__ C,
                                        const float* __restrict__ bias,
                                        short* sAmem, short* sBmem) {
  const int tid = threadIdx.x;
  const int lane = tid & 63;
  const int w = tid >> 6;
  const int a = lane & 15;
  const int g = (lane >> 4) & 3;
  const int wm = w >> 1;   // 0..3 -> 64-row slab
  const int wn = w & 1;    // 0..1 -> 96-col slab

  short* const A0h0 = sAmem;              // buf0 kh0
  short* const A0h1 = sAmem + 8192;       // buf0 kh1
  short* const A1h0 = sAmem + 16384;      // buf1 kh0
  short* const A1h1 = sAmem + 24576;      // buf1 kh1
  short* const B0h0 = sBmem;
  short* const B0h1 = sBmem + 6144;
  short* const B1h0 = sBmem + 12288;
  short* const B1h1 = sBmem + 18432;

  // A half-tile: 256 rows x 32 K = 1024 slots, 2 loads/thread.
  auto stageA = [&](int kbase, short* lblk) {
#pragma unroll
    for (int l = 0; l < 2; l++) {
      const int t = l * 512 + tid;
      const int row = t >> 2;
      const int ls = (t & 3) ^ ((row >> 1) & 3);
      async_ld16(Ab + (size_t)row * KDIM + kbase + ls * 8,
                 lblk + (l * 512 + w * 64) * 8);
    }
  };
  // B half-tile: 192 rows x 32 K = 768 slots; waves 0-3 do the second round.
  auto stageB = [&](int kbase, short* lblk) {
    {
      const int t = tid;
      const int row = t >> 2;
      const int ls = (t & 3) ^ ((row >> 1) & 3);
      async_ld16(Bb + (size_t)row * KDIM + kbase + ls * 8,
                 lblk + (w * 64) * 8);
    }
    if (w < 4) {
      const int t = 512 + tid;
      const int row = t >> 2;
      const int ls = (t & 3) ^ ((row >> 1) & 3);
      async_ld16(Bb + (size_t)row * KDIM + kbase + ls * 8,
                 lblk + (512 + w * 64) * 8);
    }
  };
  auto frag = [&](const short* lblk, int R) -> short8 {
    return *(const short8*)(lblk + R * 32 + ((g ^ ((R >> 1) & 3)) * 8));
  };

  f32x4 acc[4][6] = {};

  // Prologue: stage tile0 into buf0, drain, barrier.
  stageA(0, A0h0);
  stageA(32, A0h1);
  stageB(0, B0h0);
  stageB(32, B0h1);
  asm volatile("s_waitcnt vmcnt(0)" ::: "memory");
  __builtin_amdgcn_s_barrier();

  const int ra = wm * 64 + a;
  const int rb = wn * 96 + a;

  // One K-tile: read 20 frags (4 sched-pinned groups), stage tile u+1 into
  // the other buffer, then 4 MFMA groups gated by counted lgkmcnt.
  auto ktile = [&](int u, const short* cA0, const short* cA1,
                   const short* cB0, const short* cB1,
                   short* nA0, short* nA1, short* nB0, short* nB1) {
    short8 af0[4], af1[4], b0a[3], b0b[3], b1a[3], b1b[3];
    // Read group 1: af0 (4) + b0a (3)  -> reads #1-7
#pragma unroll
    for (int i = 0; i < 4; i++) af0[i] = frag(cA0, ra + i * 16);
#pragma unroll
    for (int j = 0; j < 3; j++) b0a[j] = frag(cB0, rb + j * 16);
    __builtin_amdgcn_sched_barrier(0);
    // Read group 2: b0b (3)            -> reads #8-10
#pragma unroll
    for (int j = 0; j < 3; j++) b0b[j] = frag(cB0, rb + (j + 3) * 16);
    __builtin_amdgcn_sched_barrier(0);
    // Read group 3: af1 (4) + b1a (3)  -> reads #11-17
#pragma unroll
    for (int i = 0; i < 4; i++) af1[i] = frag(cA1, ra + i * 16);
#pragma unroll
    for (int j = 0; j < 3; j++) b1a[j] = frag(cB1, rb + j * 16);
    __builtin_amdgcn_sched_barrier(0);
    // Read group 4: b1b (3)            -> reads #18-20
#pragma unroll
    for (int j = 0; j < 3; j++) b1b[j] = frag(cB1, rb + (j + 3) * 16);
    __builtin_amdgcn_sched_barrier(0);
    // Stage tile u+1 into the other buffer (vm ops; lgkm counts unaffected).
    if (u + 1 < NT_K) {
      const int kb = (u + 1) * 64;
      stageA(kb, nA0);
      stageA(kb + 32, nA1);
      stageB(kb, nB0);
      stageB(kb + 32, nB1);
    }
    __builtin_amdgcn_sched_barrier(0);
    // G1: kh0 x j0-2 — needs reads #1-7 -> 13 may remain outstanding.
    asm volatile("s_waitcnt lgkmcnt(13)" ::: "memory");
    __builtin_amdgcn_sched_barrier(0);
    __builtin_amdgcn_s_setprio(1);
#pragma unroll
    for (int i = 0; i < 4; i++)
#pragma unroll
      for (int j = 0; j < 3; j++)
        acc[i][j] = __builtin_amdgcn_mfma_f32_16x16x32_bf16(af0[i], b0a[j], acc[i][j], 0, 0, 0);
    __builtin_amdgcn_s_setprio(0);
    __builtin_amdgcn_sched_barrier(0);
    // G2: kh0 x j3-5 — needs through read #10.
    asm volatile("s_waitcnt lgkmcnt(10)" ::: "memory");
    __builtin_amdgcn_sched_barrier(0);
    __builtin_amdgcn_s_setprio(1);
#pragma unroll
    for (int i = 0; i < 4; i++)
#pragma unroll
      for (int j = 0; j < 3; j++)
        acc[i][j + 3] = __builtin_amdgcn_mfma_f32_16x16x32_bf16(af0[i], b0b[j], acc[i][j + 3], 0, 0, 0);
    __builtin_amdgcn_s_setprio(0);
    __builtin_amdgcn_sched_barrier(0);
    // G3: kh1 x j0-2 — needs through read #17.
    asm volatile("s_waitcnt lgkmcnt(3)" ::: "memory");
    __builtin_amdgcn_sched_barrier(0);
    __builtin_amdgcn_s_setprio(1);
#pragma unroll
    for (int i = 0; i < 4; i++)
#pragma unroll
      for (int j = 0; j < 3; j++)
        acc[i][j] = __builtin_amdgcn_mfma_f32_16x16x32_bf16(af1[i], b1a[j], acc[i][j], 0, 0, 0);
    __builtin_amdgcn_s_setprio(0);
    __builtin_amdgcn_sched_barrier(0);
    // G4: kh1 x j3-5 — needs all reads.
    asm volatile("s_waitcnt lgkmcnt(0)" ::: "memory");
    __builtin_amdgcn_sched_barrier(0);
    __builtin_amdgcn_s_setprio(1);
#pragma unroll
    for (int i = 0; i < 4; i++)
#pragma unroll
      for (int j = 0; j < 3; j++)
        acc[i][j + 3] = __builtin_amdgcn_mfma_f32_16x16x32_bf16(af1[i], b1b[j], acc[i][j + 3], 0, 0, 0);
    __builtin_amdgcn_s_setprio(0);
    __builtin_amdgcn_sched_barrier(0);
    // All this tile's stages (issued ~a full K-tile ago) must land before any
    // wave reads them next tile: per-wave vmcnt(0) THEN barrier.
    asm volatile("s_waitcnt vmcnt(0)" ::: "memory");
    __builtin_amdgcn_s_barrier();
  };

#pragma unroll 1
  for (int u = 0; u < NT_K; u += 2) {
    ktile(u,     A0h0, A0h1, B0h0, B0h1, A1h0, A1h1, B1h0, B1h1);
    ktile(u + 1, A1h0, A1h1, B1h0, B1h1, A0h0, A0h1, B0h0, B0h1);
  }

  // Epilogue. C/D layout: col = lane&15, row = (lane>>4)*4 + reg.
  if constexpr (TRANS) {
#pragma unroll
    for (int i = 0; i < 4; i++)
#pragma unroll
      for (int j = 0; j < 6; j++) {
        const int col = wn * 96 + j * 16 + a;
        const float bv = bias ? bias[col] : 0.0f;
        s16x4 pk;
#pragma unroll
        for (int r = 0; r < 4; r++) pk[r] = bf16_bits(acc[i][j][r] + bv);
        *(s16x4*)((short*)C + (size_t)col * S_ALL + wm * 64 + i * 16 + g * 4) = pk;
      }
  } else {
#pragma unroll
    for (int i = 0; i < 4; i++)
#pragma unroll
      for (int j = 0; j < 6; j++) {
        const int col = wn * 96 + j * 16 + a;
        const float bv = bias ? bias[col] : 0.0f;
#pragma unroll
        for (int r = 0; r < 4; r++) {
          const int row = wm * 64 + i * 16 + g * 4 + r;
          C[(size_t)row * KDIM + col] = (OutT)(acc[i][j][r] + bv);
        }
      }
  }
}

// Fused QKV projection: 1D grid 480 = 10 row-tiles x 48 col-tiles (192 wide),
// XCD-bijective swizzle (480 % 8 == 0), bn-fastest for shared A in L2.
__global__ __launch_bounds__(512, 2) void qkv_kernel(
    const bf16* __restrict__ XE, const bf16* __restrict__ Wc,
    const float* __restrict__ bq, const float* __restrict__ bk, const float* __restrict__ bv,
    bf16* __restrict__ Q, bf16* __restrict__ K, bf16* __restrict__ VT) {
  __shared__ alignas(16) short sAmem[4 * 8192];
  __shared__ alignas(16) short sBmem[4 * 6144];
  const int bid = blockIdx.x;
  const int wk_ = (bid & 7) * 60 + (bid >> 3);
  const int bm = wk_ / 48;        // 0..9  (256 rows each)
  const int bn = wk_ % 48;        // bn-fastest within an XCD chunk
  const int which = bn / 16;      // 0=Q 1=K 2=V
  const int nc = (bn % 16) * QBN;
  const bool txt = bm < 2;        // rows 0..511 = enc
  const bf16* W = Wc + (size_t)(txt ? (3 + which) : which) * WELEM + (size_t)nc * KDIM;
  const float* bias = nullptr;
  if (txt) bias = ((which == 0) ? bq : (which == 1) ? bk : bv) + nc;
  const int crow = bm * 256;
  const bf16* A = XE + (size_t)crow * KDIM;
  if (which == 2) {
    gemm256<bf16, true>(A, W, VT + (size_t)nc * S_ALL + crow, bias, sAmem, sBmem);
  } else {
    bf16* Out = (which == 0) ? Q : K;
    gemm256<bf16, false>(A, W, Out + (size_t)crow * KDIM + nc, bias, sAmem, sBmem);
  }
}

// ---------------------------------------------------------------------------
// 128x128 NT GEMM tile core (outproj only; 480 blocks, 2/CU, co-resident).
// ---------------------------------------------------------------------------
template <typename OutT, bool TRANS>
__device__ __forceinline__ void gemm_tile(const bf16* __restrict__ A,
                                          const bf16* __restrict__ B,
                                          OutT* __restrict__ C,
                                          const float* __restrict__ bias) {
  __shared__ alignas(16) short sA[128 * 32];
  __shared__ alignas(16) short sB[128 * 32];
  const int tid = threadIdx.x;
  const int lane = tid & 63;
  const int w = tid >> 6;
  const int a = lane & 15;
  const int g = lane >> 4;
  const int wm = (w >> 1) * 64;
  const int wn = (w & 1) * 64;

  f32x4 acc[4][4] = {};

  const int s0 = tid, s1 = tid + 256;
  const int r0 = s0 >> 2, b0 = (s0 & 3) ^ ((r0 >> 1) & 3);
  const int r1 = s1 >> 2, b1 = (s1 & 3) ^ ((r1 >> 1) & 3);
  const bf16* gA0 = A + (size_t)r0 * KDIM + b0 * 8;
  const bf16* gA1 = A + (size_t)r1 * KDIM + b1 * 8;
  const bf16* gB0 = B + (size_t)r0 * KDIM + b0 * 8;
  const bf16* gB1 = B + (size_t)r1 * KDIM + b1 * 8;
  short* lA0 = sA + (w * 64) * 8;
  short* lA1 = sA + (256 + w * 64) * 8;
  short* lB0 = sB + (w * 64) * 8;
  short* lB1 = sB + (256 + w * 64) * 8;

  for (int k0 = 0; k0 < KDIM; k0 += 32) {
    __syncthreads();
    async_ld16(gA0 + k0, lA0);
    async_ld16(gA1 + k0, lA1);
    async_ld16(gB0 + k0, lB0);
    async_ld16(gB1 + k0, lB1);
    __syncthreads();
    short8 af[4], bfg[4];
#pragma unroll
    for (int i = 0; i < 4; i++) {
      const int R = wm + i * 16 + a;
      af[i] = *(const short8*)(sA + R * 32 + ((g ^ ((R >> 1) & 3)) * 8));
    }
#pragma unroll
    for (int j = 0; j < 4; j++) {
      const int R = wn + j * 16 + a;
      bfg[j] = *(const short8*)(sB + R * 32 + ((g ^ ((R >> 1) & 3)) * 8));
    }
#pragma unroll
    for (int i = 0; i < 4; i++)
#pragma unroll
      for (int j = 0; j < 4; j++)
        acc[i][j] = __builtin_amdgcn_mfma_f32_16x16x32_bf16(af[i], bfg[j], acc[i][j], 0, 0, 0);
  }

  if constexpr (TRANS) {
#pragma unroll
    for (int i = 0; i < 4; i++)
#pragma unroll
      for (int j = 0; j < 4; j++) {
        const int col = wn + j * 16 + a;
        const float bv = bias ? bias[col] : 0.0f;
        s16x4 pk;
#pragma unroll
        for (int r = 0; r < 4; r++) pk[r] = bf16_bits(acc[i][j][r] + bv);
        *(s16x4*)((short*)C + (size_t)col * S_ALL + wm + i * 16 + g * 4) = pk;
      }
  } else {
#pragma unroll
    for (int i = 0; i < 4; i++)
#pragma unroll
      for (int j = 0; j < 4; j++) {
        const int col = wn + j * 16 + a;
        const float bv = bias ? bias[col] : 0.0f;
#pragma unroll
        for (int r = 0; r < 4; r++) {
          const int row = wm + i * 16 + g * 4 + r;
          C[(size_t)row * KDIM + col] = (OutT)(acc[i][j][r] + bv);
        }
      }
  }
}

// Output projection: grid (20, 24). d_out: img (2048x3072) then enc (512x3072), f32.
__global__ __launch_bounds__(256) void outproj_kernel(
    const bf16* __restrict__ Obuf, const bf16* __restrict__ Wc,
    const float* __restrict__ b_out, const float* __restrict__ b_add,
    float* __restrict__ out) {
  const int bm = blockIdx.x;
  const int bn = blockIdx.y;
  const bool txt = bm < 4;
  const bf16* A = Obuf + (size_t)bm * 128 * KDIM;
  const bf16* W = Wc + (size_t)(txt ? 7 : 6) * WELEM;
  const float* bias = txt ? b_add : b_out;
  float* C = txt ? (out + (size_t)S_IMG * KDIM + (size_t)bm * 128 * KDIM)
                 : (out + (size_t)(bm - 4) * 128 * KDIM);
  gemm_tile<float, false>(A, W + (size_t)bn * 128 * KDIM, C + bn * 128, bias + bn * 128);
}

// RMS-norm + RoPE in-place. Q additionally pre-scaled by (1/sqrt(128))*log2(e)
// so the QK^T MFMA in flash emits exp2-domain scores directly.
__global__ __launch_bounds__(256) void norm_rope_kernel(
    bf16* __restrict__ Q, bf16* __restrict__ K,
    const float* __restrict__ rc, const float* __restrict__ rs,
    const float* __restrict__ nqw, const float* __restrict__ nkw,
    const float* __restrict__ naqw, const float* __restrict__ nakw) {
  const int row = blockIdx.x;
  const int h = blockIdx.y * 4 + (threadIdx.x >> 6);
  const int t = threadIdx.x & 63;
  const long base = (long)row * KDIM + h * HDIM;
  const int d0 = 2 * t, d1 = d0 + 1;
  const bool txt = row < S_TXT;
  const float QSCL = 0.08838834764831845f * 1.4426950408889634f;
  float qa = (float)Q[base + d0], qb = (float)Q[base + d1];
  float ka = (float)K[base + d0], kb = (float)K[base + d1];
  float sq = qa * qa + qb * qb;
  float sk = ka * ka + kb * kb;
#pragma unroll
  for (int m = 1; m < 64; m <<= 1) {
    sq += __shfl_xor(sq, m);
    sk += __shfl_xor(sk, m);
  }
  const float rq = rsqrtf(sq * (1.0f / 128.0f) + 1e-5f) * QSCL;
  const float rk = rsqrtf(sk * (1.0f / 128.0f) + 1e-5f);
  const float* qw = txt ? naqw : nqw;
  const float* kw = txt ? nakw : nkw;
  const float c0 = rc[row * HDIM + d0], c1 = rc[row * HDIM + d1];
  const float s0 = rs[row * HDIM + d0], s1 = rs[row * HDIM + d1];
  const float qn0 = qa * rq * qw[d0], qn1 = qb * rq * qw[d1];
  const float kn0 = ka * rk * kw[d0], kn1 = kb * rk * kw[d1];
  Q[base + d0] = (bf16)(qn0 * c0 - qn1 * s0);
  Q[base + d1] = (bf16)(qn1 * c1 + qn0 * s1);
  K[base + d0] = (bf16)(kn0 * c0 - kn1 * s0);
  K[base + d1] = (bf16)(kn1 * c1 + kn0 * s1);
}

// ---------------------------------------------------------------------------
// Flash attention, split-KV x3, FIXED-MAX softmax (p = exp2(score), scores
// bounded -> f32-safe). grid (20 q-tiles, 24 heads, 3 splits), 4 waves.
// S^T = K*Q^T so P lands A-operand-friendly; no cross-lane ops in KV loop.
// ---------------------------------------------------------------------------
__global__ __launch_bounds__(256) void flash_kernel(
    const bf16* __restrict__ Q, const bf16* __restrict__ Kb,
    const bf16* __restrict__ VT,
    bf16* __restrict__ Op0, bf16* __restrict__ Op1, bf16* __restrict__ Op2,
    float* __restrict__ L) {
  __shared__ alignas(16) short sK[64 * 128];
  __shared__ alignas(16) short sVT[128 * 64];
  __shared__ alignas(16) short sP[4][32 * 72];
  const int tid = threadIdx.x;
  const int lane = tid & 63;
  const int w = tid >> 6;
  const int a = lane & 15;
  const int g = lane >> 4;
  const int qt = blockIdx.x;
  const int h = blockIdx.y;
  const int split = blockIdx.z;
  const int it0 = split * 13;
  const int it1 = (split == 2) ? 40 : (it0 + 13);
  const int qrow0 = qt * 128 + w * 32;
  short* const sPw = sP[w];

  short8 qf[2][4];
#pragma unroll
  for (int mi = 0; mi < 2; mi++)
#pragma unroll
    for (int kk = 0; kk < 4; kk++)
      qf[mi][kk] = *(const short8*)(Q + (size_t)(qrow0 + mi * 16 + a) * KDIM + h * HDIM + kk * 32 + g * 8);

  f32x4 oacc[2][8] = {};
  float lsum[2] = {0.0f, 0.0f};

  for (int it = it0; it < it1; ++it) {
    const int kv0 = it * 64;
    __syncthreads();
#pragma unroll
    for (int is = 0; is < 4; is++) {
      const int s = is * 256 + w * 64 + lane;
      const int kr = s >> 4, p = s & 15;
      const int lb = (p - (kr & 7)) & 15;
      async_ld16(Kb + (size_t)(kv0 + kr) * KDIM + h * HDIM + lb * 8,
                 sK + (is * 256 + w * 64) * 8);
    }
#pragma unroll
    for (int is = 0; is < 4; is++) {
      const int s = is * 256 + w * 64 + lane;
      const int dr = s >> 3, p = s & 7;
      const int lb = (p - (dr & 7)) & 7;
      async_ld16(VT + (size_t)(h * HDIM + dr) * S_ALL + kv0 + lb * 8,
                 sVT + (is * 256 + w * 64) * 8);
    }
    __syncthreads();

    f32x4 st[4][2] = {};
#pragma unroll
    for (int kk = 0; kk < 4; kk++) {
      short8 kf[4];
#pragma unroll
      for (int ni = 0; ni < 4; ni++) {
        const int kr = ni * 16 + a;
        const int p = ((kk * 4 + g) + (kr & 7)) & 15;
        kf[ni] = *(const short8*)(sK + kr * 128 + p * 8);
      }
#pragma unroll
      for (int ni = 0; ni < 4; ni++)
#pragma unroll
        for (int mi = 0; mi < 2; mi++)
          st[ni][mi] = __builtin_amdgcn_mfma_f32_16x16x32_bf16(kf[ni], qf[mi][kk], st[ni][mi], 0, 0, 0);
    }

#pragma unroll
    for (int mi = 0; mi < 2; mi++)
#pragma unroll
      for (int ni = 0; ni < 4; ni++) {
        s16x4 pk;
#pragma unroll
        for (int r = 0; r < 4; r++) {
          const float p = exp2f(st[ni][mi][r]);
          lsum[mi] += p;
          pk[r] = bf16_bits(p);
        }
        *(s16x4*)(sPw + (mi * 16 + a) * 72 + ni * 16 + g * 4) = pk;
      }

#pragma unroll
    for (int ks = 0; ks < 2; ks++) {
      short8 pf[2];
#pragma unroll
      for (int mi = 0; mi < 2; mi++)
        pf[mi] = *(const short8*)(sPw + (mi * 16 + a) * 72 + ks * 32 + g * 8);
#pragma unroll
      for (int nd = 0; nd < 8; nd++) {
        const int dr = nd * 16 + a;
        const int p = ((ks * 4 + g) + (dr & 7)) & 7;
        const short8 vf = *(const short8*)(sVT + dr * 64 + p * 8);
#pragma unroll
        for (int mi = 0; mi < 2; mi++)
          oacc[mi][nd] = __builtin_amdgcn_mfma_f32_16x16x32_bf16(pf[mi], vf, oacc[mi][nd], 0, 0, 0);
      }
    }
  }

#pragma unroll
  for (int mi = 0; mi < 2; mi++) {
    lsum[mi] += __shfl_xor(lsum[mi], 16);
    lsum[mi] += __shfl_xor(lsum[mi], 32);
  }
  bf16* __restrict__ Op = (split == 0) ? Op0 : (split == 1) ? Op1 : Op2;
#pragma unroll
  for (int mi = 0; mi < 2; mi++) {
#pragma unroll
    for (int r = 0; r < 4; r++) {
      const float inv = 1.0f / __shfl(lsum[mi], g * 4 + r);
      const size_t row = qrow0 + mi * 16 + g * 4 + r;
#pragma unroll
      for (int nd = 0; nd < 8; nd++)
        Op[row * KDIM + h * HDIM + nd * 16 + a] = (bf16)(oacc[mi][nd][r] * inv);
    }
    if (g == 0)
      L[((size_t)split * NHEADS + h) * S_ALL + qrow0 + mi * 16 + a] = lsum[mi];
  }
}

// Merge 3 KV-split partials: O = sum(l_i * O_i) / sum(l_i). In-place into O0.
__global__ __launch_bounds__(256) void merge_kernel(
    bf16* __restrict__ O0, const bf16* __restrict__ O1, const bf16* __restrict__ O2,
    const float* __restrict__ L) {
  const size_t i0 = ((size_t)blockIdx.x * 256 + threadIdx.x) * 8;
  const int row = (int)(i0 / KDIM);
  const int h = (int)((i0 % KDIM) >> 7);
  const float l0 = L[((size_t)0 * NHEADS + h) * S_ALL + row];
  const float l1 = L[((size_t)1 * NHEADS + h) * S_ALL + row];
  const float l2 = L[((size_t)2 * NHEADS + h) * S_ALL + row];
  const float inv = 1.0f / (l0 + l1 + l2);
  const float w0 = l0 * inv, w1 = l1 * inv, w2 = l2 * inv;
  const short8 v0 = *(const short8*)(O0 + i0);
  const short8 v1 = *(const short8*)(O1 + i0);
  const short8 v2 = *(const short8*)(O2 + i0);
  short8 o;
#pragma unroll
  for (int u = 0; u < 8; u++)
    o[u] = bf16_bits(w0 * bits_f32(v0[u]) + w1 * bits_f32(v1[u]) + w2 * bits_f32(v2[u]));
  *(short8*)(O0 + i0) = o;
}

extern "C" void kernel_launch(void* const* d_in, const int* in_sizes, int n_in,
                              void* d_out, int out_size, void* d_ws, size_t ws_size,
                              hipStream_t stream) {
  const float* x    = (const float*)d_in[0];
  const float* enc  = (const float*)d_in[1];
  const float* rc   = (const float*)d_in[2];
  const float* rs   = (const float*)d_in[3];
  const float* wq   = (const float*)d_in[4];
  const float* wk   = (const float*)d_in[5];
  const float* wv   = (const float*)d_in[6];
  const float* waq  = (const float*)d_in[7];
  const float* wak  = (const float*)d_in[8];
  const float* wav  = (const float*)d_in[9];
  const float* bq   = (const float*)d_in[10];
  const float* bk   = (const float*)d_in[11];
  const float* bv   = (const float*)d_in[12];
  const float* nqw  = (const float*)d_in[13];
  const float* nkw  = (const float*)d_in[14];
  const float* naqw = (const float*)d_in[15];
  const float* nakw = (const float*)d_in[16];
  const float* w_out     = (const float*)d_in[17];
  const float* b_out     = (const float*)d_in[18];
  const float* w_add_out = (const float*)d_in[19];
  const float* b_add_out = (const float*)d_in[20];

  // ws layout (bf16): Wc[8*WELEM] | XE(->Opart2) | Q | K | VT | Obuf(=Opart0)
  //                   | Opart1 | L(f32)   — ~235 MiB total.
  bf16* Wc   = (bf16*)d_ws;
  bf16* XE   = Wc + (size_t)8 * WELEM;
  bf16* Q    = XE + AELEM;
  bf16* K    = Q + AELEM;
  bf16* VT   = K + AELEM;
  bf16* Obuf = VT + AELEM;           // Opart split 0
  bf16* Op1  = Obuf + AELEM;         // Opart split 1
  bf16* Op2  = XE;                   // reuse XE (dead after qkv)
  float* L   = (float*)(Op1 + AELEM);

  cast_weights_kernel<<<dim3(WELEM / 2048, 8), 256, 0, stream>>>(
      wq, wk, wv, waq, wak, wav, w_out, w_add_out, Wc);
  cast_acts_kernel<<<dim3(AELEM / 2048), 256, 0, stream>>>(x, enc, XE);

  qkv_kernel<<<dim3(480), dim3(512), 0, stream>>>(XE, Wc, bq, bk, bv, Q, K, VT);
  norm_rope_kernel<<<dim3(S_ALL, 6), 256, 0, stream>>>(Q, K, rc, rs, nqw, nkw, naqw, nakw);
  flash_kernel<<<dim3(20, NHEADS, NSPLIT), 256, 0, stream>>>(Q, K, VT, Obuf, Op1, Op2, L);
  merge_kernel<<<dim3(AELEM / 2048), 256, 0, stream>>>(Obuf, Op1, Op2, L);
  outproj_kernel<<<dim3(20, NHEADS), 256, 0, stream>>>(Obuf, Wc, b_out, b_add_out,
                                                       (float*)d_out);
}